// Round 7
// baseline (893.759 us; speedup 1.0000x reference)
//
#include <hip/hip_runtime.h>

#define NN 100000
#define NE 1600000
#define NEO 400000
#define HID 64
#define NL 6
#define BN_EPS 1e-5f

#define SPMM_BLOCKS 2048
#define SCAN_BS 512
#define SCAN_NB 196   // ceil(100000/512)
#define GRP_ROWS 12500          // NN/8 rows per XCD group
#define BUILD_BPG 784           // blocks per group for hist/build

// ---- d_ws layout (float offsets): 70.4MB ----
#define OFF_ECOL 0                        // NE ints
#define OFF_XE   NE                       // NN*64 f
#define OFF_AGG  (OFF_XE + NN * HID)      // NN*64 f
#define OFF_HWB  (OFF_AGG + NN * HID)     // NN*64 bf16 = NN*32 f

// ---- d_out head used as scratch (dead before k_out overwrites) ----
#define OD_DINV   0                      // NN f
#define OD_ROWPTR 100000                 // NN+1 ints (rounded 100352)
#define OD_CC     200352                 // NN ints (counts, then cursors)
#define OD_BSUM   300352                 // 256 ints
#define OD_SS     300608                 // 128 f (scale/shift)
#define OD_SUMS   300736                 // 16*128 doubles

#define NTL(p) __builtin_nontemporal_load(p)
#define NTS(v, p) __builtin_nontemporal_store(v, p)

typedef float v4f __attribute__((ext_vector_type(4)));   // native vec: NT-store legal

static __device__ __forceinline__ unsigned short f2bf(float f) {
    unsigned u = __float_as_uint(f);
    unsigned r = (u + 0x7FFF + ((u >> 16) & 1)) >> 16;  // RNE
    return (unsigned short)r;
}
static __device__ __forceinline__ float bflo(unsigned u) {
    return __uint_as_float(u << 16);
}
static __device__ __forceinline__ float bfhi(unsigned u) {
    return __uint_as_float(u & 0xFFFF0000u);
}

// XCD-partitioned histogram; dst streamed non-temporally (protect cnt lines in L2)
__global__ void k_hist(const int* __restrict__ dst, int* __restrict__ cnt) {
    int g = blockIdx.x & 7;
    int b = blockIdx.x >> 3;
    int lo = g * GRP_ROWS, hi = lo + GRP_ROWS;
    for (int e = b * blockDim.x + threadIdx.x; e < NE; e += BUILD_BPG * blockDim.x) {
        int d = NTL(&dst[e]);
        if (d >= lo && d < hi) atomicAdd(&cnt[d], 1);
    }
}

__global__ void k_scanA(const int* __restrict__ cnt, int* __restrict__ rowptr,
                        int* __restrict__ bsum, float* __restrict__ dinv) {
    __shared__ int sh[SCAN_BS];
    int t = threadIdx.x;
    int i = blockIdx.x * SCAN_BS + t;
    int v = (i < NN) ? cnt[i] : 0;
    sh[t] = v;
    __syncthreads();
    for (int off = 1; off < SCAN_BS; off <<= 1) {
        int a = (t >= off) ? sh[t - off] : 0;
        __syncthreads();
        sh[t] += a;
        __syncthreads();
    }
    if (i < NN) {
        rowptr[i] = sh[t] - v;
        dinv[i] = rsqrtf((float)(v + 1));   // deg = in-deg + self-loop
    }
    if (t == SCAN_BS - 1) bsum[blockIdx.x] = sh[t];
}

__global__ void k_scanB(int* __restrict__ bsum) {
    __shared__ int sh[256];
    int t = threadIdx.x;
    int v = (t < SCAN_NB) ? bsum[t] : 0;
    sh[t] = v;
    __syncthreads();
    for (int off = 1; off < 256; off <<= 1) {
        int a = (t >= off) ? sh[t - off] : 0;
        __syncthreads();
        sh[t] += a;
        __syncthreads();
    }
    if (t < SCAN_NB) bsum[t] = (t == 0) ? 0 : sh[t - 1];
}

__global__ void k_scanC(int* __restrict__ rowptr, const int* __restrict__ bsum,
                        int* __restrict__ cursor) {
    int i = blockIdx.x * SCAN_BS + threadIdx.x;
    if (i < NN) {
        int rp = rowptr[i] + bsum[blockIdx.x];
        rowptr[i] = rp;
        cursor[i] = rp;
    }
    if (i == 0) rowptr[NN] = NE;
}

// XCD-partitioned CSR scatter; edge streams non-temporal so ecol lines stay in L2
__global__ void k_build(const int* __restrict__ src, const int* __restrict__ dst,
                        int* __restrict__ cursor, int* __restrict__ ecol) {
    int g = blockIdx.x & 7;
    int b = blockIdx.x >> 3;
    int lo = g * GRP_ROWS, hi = lo + GRP_ROWS;
    for (int e = b * blockDim.x + threadIdx.x; e < NE; e += BUILD_BPG * blockDim.x) {
        int d = NTL(&dst[e]);
        if (d >= lo && d < hi) {
            int pos = atomicAdd(&cursor[d], 1);
            ecol[pos] = NTL(&src[e]);
        }
    }
}

// xe = x[NN,16] @ W[16,64] + b
__global__ void k_embed(const float* __restrict__ x, const float* __restrict__ W,
                        const float* __restrict__ b, float* __restrict__ xe) {
    __shared__ float Ws[16 * 64];
    __shared__ float bs[64];
    int t = threadIdx.x;
    for (int i = t; i < 16 * 64; i += 256) Ws[i] = W[i];
    if (t < 64) bs[t] = b[t];
    __syncthreads();
    int c = t & 63, r = t >> 6;
    int n0 = blockIdx.x * 64;
    for (int n = n0 + r; n < n0 + 64 && n < NN; n += 4) {
        const float* xr = x + n * 16;
        float acc = bs[c];
#pragma unroll
        for (int k = 0; k < 16; k++) acc = fmaf(xr[k], Ws[k * 64 + c], acc);
        NTS(acc, &xe[n * 64 + c]);
    }
}

// fused: xe += relu(agg*sc+sh) (prev BN, if apply); hwb = bf16(dinv*(xe@W))
__global__ void k_hw(const float* __restrict__ xeIn, float* __restrict__ xe,
                     const float* __restrict__ W, const float* __restrict__ dinv,
                     const float* __restrict__ agg, const float* __restrict__ ss,
                     unsigned short* __restrict__ hwb, double* __restrict__ sums,
                     int apply) {
    __shared__ float Ws[64 * 64];     // Ws[k][c]
    __shared__ float Xs[64 * 65];     // Xs[n][k], +1 pad
    int t = threadIdx.x;
    if (blockIdx.x == 0) {
        for (int i = t; i < 16 * 128; i += 256) sums[i] = 0.0;
    }
#pragma unroll
    for (int i = 0; i < 4; i++)
        ((float4*)Ws)[t + i * 256] = ((const float4*)W)[t + i * 256];
    int c = t & 63, rr = t >> 6;
    int n0 = blockIdx.x * 64;
#pragma unroll
    for (int i = 0; i < 16; i++) {
        int rl = i * 4 + rr;
        int n = n0 + rl;
        float xv = 0.f;
        if (n < NN) {
            xv = NTL(&xeIn[n * 64 + c]);
            if (apply) {
                float v = fmaf(NTL(&agg[n * 64 + c]), ss[c], ss[64 + c]);
                xv += fmaxf(v, 0.f);
                NTS(xv, &xe[n * 64 + c]);
            }
        }
        Xs[rl * 65 + c] = xv;
    }
    __syncthreads();

    int r0 = (t >> 4) * 4, c0 = (t & 15) * 4;
    float acc[4][4];
#pragma unroll
    for (int a = 0; a < 4; a++)
#pragma unroll
        for (int b = 0; b < 4; b++) acc[a][b] = 0.f;
    for (int k = 0; k < 64; k++) {
        float4 wv = *(const float4*)&Ws[k * 64 + c0];
        float x0 = Xs[(r0 + 0) * 65 + k];
        float x1 = Xs[(r0 + 1) * 65 + k];
        float x2 = Xs[(r0 + 2) * 65 + k];
        float x3 = Xs[(r0 + 3) * 65 + k];
        acc[0][0] = fmaf(x0, wv.x, acc[0][0]); acc[0][1] = fmaf(x0, wv.y, acc[0][1]);
        acc[0][2] = fmaf(x0, wv.z, acc[0][2]); acc[0][3] = fmaf(x0, wv.w, acc[0][3]);
        acc[1][0] = fmaf(x1, wv.x, acc[1][0]); acc[1][1] = fmaf(x1, wv.y, acc[1][1]);
        acc[1][2] = fmaf(x1, wv.z, acc[1][2]); acc[1][3] = fmaf(x1, wv.w, acc[1][3]);
        acc[2][0] = fmaf(x2, wv.x, acc[2][0]); acc[2][1] = fmaf(x2, wv.y, acc[2][1]);
        acc[2][2] = fmaf(x2, wv.z, acc[2][2]); acc[2][3] = fmaf(x2, wv.w, acc[2][3]);
        acc[3][0] = fmaf(x3, wv.x, acc[3][0]); acc[3][1] = fmaf(x3, wv.y, acc[3][1]);
        acc[3][2] = fmaf(x3, wv.z, acc[3][2]); acc[3][3] = fmaf(x3, wv.w, acc[3][3]);
    }
#pragma unroll
    for (int a = 0; a < 4; a++) {
        int n = n0 + r0 + a;
        if (n < NN) {
            float di = dinv[n];
            float v0 = acc[a][0] * di, v1 = acc[a][1] * di;
            float v2 = acc[a][2] * di, v3 = acc[a][3] * di;
            uint2 pk;
            pk.x = ((unsigned)f2bf(v1) << 16) | f2bf(v0);
            pk.y = ((unsigned)f2bf(v3) << 16) | f2bf(v2);
            *(uint2*)(hwb + n * 64 + c0) = pk;   // cached: gathered 16x by spmm
        }
    }
}

// agg[d] = dinv[d]*(hwb[d] + sum_{s in N(d)} hwb[s]); fused BN stats.
// Wave = 1 row; 4 groups of 16 lanes stride the edge list; lane q owns ch 4q..4q+3.
__global__ void k_spmm(const int* __restrict__ rowptr, const int* __restrict__ ecol,
                       const unsigned short* __restrict__ hwb, const float* __restrict__ dinv,
                       float* __restrict__ agg, double* __restrict__ sums) {
    int t = threadIdx.x;
    int w = t >> 6, l = t & 63;
    int grp = l >> 4, q = l & 15;
    const uint2* hw2 = (const uint2*)hwb;
    float ls0 = 0.f, ls1 = 0.f, ls2 = 0.f, ls3 = 0.f;
    float lq0 = 0.f, lq1 = 0.f, lq2 = 0.f, lq3 = 0.f;
    for (int row = blockIdx.x * 4 + w; row < NN; row += SPMM_BLOCKS * 4) {
        int p0 = __builtin_amdgcn_readfirstlane(rowptr[row]);
        int p1 = __builtin_amdgcn_readfirstlane(rowptr[row + 1]);
        uint2 sv = hw2[row * 16 + q];
        float a0 = 0.f, a1 = 0.f, a2 = 0.f, a3 = 0.f;
        int p = p0 + grp;
        for (; p + 12 < p1; p += 16) {   // unroll 4: 4 row-gathers in flight/group
            int s0 = NTL(&ecol[p]),     s1 = NTL(&ecol[p + 4]);
            int s2 = NTL(&ecol[p + 8]), s3 = NTL(&ecol[p + 12]);
            uint2 u0 = hw2[s0 * 16 + q];
            uint2 u1 = hw2[s1 * 16 + q];
            uint2 u2 = hw2[s2 * 16 + q];
            uint2 u3 = hw2[s3 * 16 + q];
            a0 += bflo(u0.x); a1 += bfhi(u0.x); a2 += bflo(u0.y); a3 += bfhi(u0.y);
            a0 += bflo(u1.x); a1 += bfhi(u1.x); a2 += bflo(u1.y); a3 += bfhi(u1.y);
            a0 += bflo(u2.x); a1 += bfhi(u2.x); a2 += bflo(u2.y); a3 += bfhi(u2.y);
            a0 += bflo(u3.x); a1 += bfhi(u3.x); a2 += bflo(u3.y); a3 += bfhi(u3.y);
        }
        for (; p < p1; p += 4) {
            int s0 = NTL(&ecol[p]);
            uint2 u0 = hw2[s0 * 16 + q];
            a0 += bflo(u0.x); a1 += bfhi(u0.x); a2 += bflo(u0.y); a3 += bfhi(u0.y);
        }
        a0 += __shfl_xor(a0, 16, 64); a0 += __shfl_xor(a0, 32, 64);
        a1 += __shfl_xor(a1, 16, 64); a1 += __shfl_xor(a1, 32, 64);
        a2 += __shfl_xor(a2, 16, 64); a2 += __shfl_xor(a2, 32, 64);
        a3 += __shfl_xor(a3, 16, 64); a3 += __shfl_xor(a3, 32, 64);
        float di = dinv[row];
        float v0 = (a0 + bflo(sv.x)) * di;
        float v1 = (a1 + bfhi(sv.x)) * di;
        float v2 = (a2 + bflo(sv.y)) * di;
        float v3 = (a3 + bfhi(sv.y)) * di;
        if (grp == 0) {
            v4f o = {v0, v1, v2, v3};
            NTS(o, (v4f*)(agg + row * 64 + 4 * q));  // streamed: protect hwb in L2
        }
        ls0 += v0; ls1 += v1; ls2 += v2; ls3 += v3;
        lq0 = fmaf(v0, v0, lq0); lq1 = fmaf(v1, v1, lq1);
        lq2 = fmaf(v2, v2, lq2); lq3 = fmaf(v3, v3, lq3);
    }
    __shared__ float Ss[4][64], Sq[4][64];
    if (grp == 0) {
        Ss[w][4 * q + 0] = ls0; Ss[w][4 * q + 1] = ls1;
        Ss[w][4 * q + 2] = ls2; Ss[w][4 * q + 3] = ls3;
        Sq[w][4 * q + 0] = lq0; Sq[w][4 * q + 1] = lq1;
        Sq[w][4 * q + 2] = lq2; Sq[w][4 * q + 3] = lq3;
    }
    __syncthreads();
    if (t < 64) {
        float a = Ss[0][t] + Ss[1][t] + Ss[2][t] + Ss[3][t];
        float b = Sq[0][t] + Sq[1][t] + Sq[2][t] + Sq[3][t];
        double* sh = sums + (blockIdx.x & 15) * 128;
        atomicAdd(&sh[t], (double)a);
        atomicAdd(&sh[64 + t], (double)b);
    }
}

__global__ void k_finalize(const double* __restrict__ sums, const float* __restrict__ gamma,
                           const float* __restrict__ beta, float* __restrict__ ss) {
    int c = threadIdx.x;  // 64 threads
    double s = 0.0, q = 0.0;
#pragma unroll
    for (int k = 0; k < 16; k++) { s += sums[k * 128 + c]; q += sums[k * 128 + 64 + c]; }
    double mean = s / (double)NN;
    double var = q / (double)NN - mean * mean;
    float sc = gamma[c] * rsqrtf((float)var + BN_EPS);
    ss[c] = sc;
    ss[64 + c] = beta[c] - (float)mean * sc;
}

// final layer: xe += relu(agg*scale + shift)
__global__ void k_apply(const float* __restrict__ agg, const float* __restrict__ ss,
                        float* __restrict__ xe) {
    int i = blockIdx.x * blockDim.x + threadIdx.x;
    if (i < NN * HID) {
        int c = i & 63;
        float v = fmaf(NTL(&agg[i]), ss[c], ss[64 + c]);
        xe[i] += fmaxf(v, 0.f);
    }
}

// out[e] = [xe[s]; xe[d]] @ fc_W + fc_b
__global__ void k_out(const int* __restrict__ esrc, const int* __restrict__ edst,
                      const float* __restrict__ xe, const float* __restrict__ fcW,
                      const float* __restrict__ fcb, float* __restrict__ out) {
    __shared__ float Ws[256];
    __shared__ float bs[2];
    int t = threadIdx.x;
    for (int i = t; i < 256; i += 256) Ws[i] = fcW[i];
    if (t < 2) bs[t] = fcb[t];
    __syncthreads();
    int e = blockIdx.x * blockDim.x + t;
    if (e < NEO) {
        int s = esrc[e], d = edst[e];
        const float4* rs = (const float4*)(xe + s * 64);
        const float4* rd = (const float4*)(xe + d * 64);
        float a0 = bs[0], a1 = bs[1];
#pragma unroll
        for (int i = 0; i < 16; i++) {
            float4 v = rs[i];
            a0 += v.x * Ws[(i * 4 + 0) * 2] + v.y * Ws[(i * 4 + 1) * 2] +
                  v.z * Ws[(i * 4 + 2) * 2] + v.w * Ws[(i * 4 + 3) * 2];
            a1 += v.x * Ws[(i * 4 + 0) * 2 + 1] + v.y * Ws[(i * 4 + 1) * 2 + 1] +
                  v.z * Ws[(i * 4 + 2) * 2 + 1] + v.w * Ws[(i * 4 + 3) * 2 + 1];
        }
#pragma unroll
        for (int i = 0; i < 16; i++) {
            float4 v = rd[i];
            a0 += v.x * Ws[(64 + i * 4 + 0) * 2] + v.y * Ws[(64 + i * 4 + 1) * 2] +
                  v.z * Ws[(64 + i * 4 + 2) * 2] + v.w * Ws[(64 + i * 4 + 3) * 2];
            a1 += v.x * Ws[(64 + i * 4 + 0) * 2 + 1] + v.y * Ws[(64 + i * 4 + 1) * 2 + 1] +
                  v.z * Ws[(64 + i * 4 + 2) * 2 + 1] + v.w * Ws[(64 + i * 4 + 3) * 2 + 1];
        }
        NTS(a0, &out[e * 2]);
        NTS(a1, &out[e * 2 + 1]);
    }
}

extern "C" void kernel_launch(void* const* d_in, const int* in_sizes, int n_in,
                              void* d_out, int out_size, void* d_ws, size_t ws_size,
                              hipStream_t stream) {
    const float* x      = (const float*)d_in[0];
    const int*   ei     = (const int*)d_in[1];
    const int*   eio    = (const int*)d_in[2];
    const float* W_emb  = (const float*)d_in[3];
    const float* b_emb  = (const float*)d_in[4];
    const float* conv_W = (const float*)d_in[5];
    // d_in[6] conv_b: cancels inside BN
    const float* bn_g   = (const float*)d_in[7];
    const float* bn_b   = (const float*)d_in[8];
    const float* fc_W   = (const float*)d_in[9];
    const float* fc_b   = (const float*)d_in[10];
    float* out = (float*)d_out;

    float* ws   = (float*)d_ws;
    int*   ecol = (int*)(ws + OFF_ECOL);
    float* xe   = ws + OFF_XE;
    float* agg  = ws + OFF_AGG;
    unsigned short* hwb = (unsigned short*)(ws + OFF_HWB);

    float* od     = (float*)d_out;
    float* dinv   = od + OD_DINV;
    int*   rowptr = (int*)(od + OD_ROWPTR);
    int*   cc     = (int*)(od + OD_CC);
    int*   bsum   = (int*)(od + OD_BSUM);
    float* ss     = od + OD_SS;
    double* sums  = (double*)(od + OD_SUMS);

    const int* src  = ei;
    const int* dst  = ei + NE;
    const int* esrc = eio;
    const int* edst = eio + NEO;

    // ---- one-time CSR build (XCD-partitioned, nt edge streams) ----
    (void)hipMemsetAsync(cc, 0, NN * sizeof(int), stream);
    k_hist<<<8 * BUILD_BPG, 256, 0, stream>>>(dst, cc);
    k_scanA<<<SCAN_NB, SCAN_BS, 0, stream>>>(cc, rowptr, bsum, dinv);
    k_scanB<<<1, 256, 0, stream>>>(bsum);
    k_scanC<<<SCAN_NB, SCAN_BS, 0, stream>>>(rowptr, bsum, cc);
    k_build<<<8 * BUILD_BPG, 256, 0, stream>>>(src, dst, cc, ecol);

    k_embed<<<(NN + 63) / 64, 256, 0, stream>>>(x, W_emb, b_emb, xe);

    for (int l = 0; l < NL; l++) {
        k_hw<<<(NN + 63) / 64, 256, 0, stream>>>(xe, xe, conv_W + l * 64 * 64, dinv,
                                                 agg, ss, hwb, sums, l > 0 ? 1 : 0);
        k_spmm<<<SPMM_BLOCKS, 256, 0, stream>>>(rowptr, ecol, hwb, dinv, agg, sums);
        k_finalize<<<1, 64, 0, stream>>>(sums, bn_g + l * 64, bn_b + l * 64, ss);
    }
    k_apply<<<(NN * HID) / 256, 256, 0, stream>>>(agg, ss, xe);

    k_out<<<(NEO + 255) / 256, 256, 0, stream>>>(esrc, edst, xe, fc_W, fc_b, out);
}

// Round 8
// 729.076 us; speedup vs baseline: 1.2259x; 1.2259x over previous
//
#include <hip/hip_runtime.h>

#define NN 100000
#define NE 1600000
#define NEO 400000
#define HID 64
#define NL 6
#define BN_EPS 1e-5f

#define SPMM_BLOCKS 2048
#define SCAN_BS 512
#define SCAN_NB 196   // ceil(100000/512)
#define GRP_ROWS 12500          // NN/8 rows per XCD group
#define BUILD_BPG 784           // blocks per group for hist/build

// ---- d_ws layout (float offsets): 70.4MB ----
#define OFF_ECOL 0                        // NE ints
#define OFF_XE   NE                       // NN*64 f
#define OFF_AGG  (OFF_XE + NN * HID)      // NN*64 f
#define OFF_HWB  (OFF_AGG + NN * HID)     // NN*64 bf16 = NN*32 f

// ---- d_out head used as scratch (dead before k_out overwrites) ----
#define OD_DINV   0                      // NN f
#define OD_ROWPTR 100000                 // NN+1 ints (rounded 100352)
#define OD_CC     200352                 // NN ints (counts, then cursors)
#define OD_BSUM   300352                 // 256 ints
#define OD_SS     300608                 // 128 f (scale/shift)
#define OD_SUMS   300736                 // 16*128 doubles

static __device__ __forceinline__ unsigned short f2bf(float f) {
    unsigned u = __float_as_uint(f);
    unsigned r = (u + 0x7FFF + ((u >> 16) & 1)) >> 16;  // RNE
    return (unsigned short)r;
}
static __device__ __forceinline__ float bflo(unsigned u) {
    return __uint_as_float(u << 16);
}
static __device__ __forceinline__ float bfhi(unsigned u) {
    return __uint_as_float(u & 0xFFFF0000u);
}

// XCD-partitioned histogram (validated win R4->R5; NT hints reverted: R7 regression)
__global__ void k_hist(const int* __restrict__ dst, int* __restrict__ cnt) {
    int g = blockIdx.x & 7;
    int b = blockIdx.x >> 3;
    int lo = g * GRP_ROWS, hi = lo + GRP_ROWS;
    for (int e = b * blockDim.x + threadIdx.x; e < NE; e += BUILD_BPG * blockDim.x) {
        int d = dst[e];
        if (d >= lo && d < hi) atomicAdd(&cnt[d], 1);
    }
}

__global__ void k_scanA(const int* __restrict__ cnt, int* __restrict__ rowptr,
                        int* __restrict__ bsum, float* __restrict__ dinv) {
    __shared__ int sh[SCAN_BS];
    int t = threadIdx.x;
    int i = blockIdx.x * SCAN_BS + t;
    int v = (i < NN) ? cnt[i] : 0;
    sh[t] = v;
    __syncthreads();
    for (int off = 1; off < SCAN_BS; off <<= 1) {
        int a = (t >= off) ? sh[t - off] : 0;
        __syncthreads();
        sh[t] += a;
        __syncthreads();
    }
    if (i < NN) {
        rowptr[i] = sh[t] - v;
        dinv[i] = rsqrtf((float)(v + 1));   // deg = in-deg + self-loop
    }
    if (t == SCAN_BS - 1) bsum[blockIdx.x] = sh[t];
}

__global__ void k_scanB(int* __restrict__ bsum) {
    __shared__ int sh[256];
    int t = threadIdx.x;
    int v = (t < SCAN_NB) ? bsum[t] : 0;
    sh[t] = v;
    __syncthreads();
    for (int off = 1; off < 256; off <<= 1) {
        int a = (t >= off) ? sh[t - off] : 0;
        __syncthreads();
        sh[t] += a;
        __syncthreads();
    }
    if (t < SCAN_NB) bsum[t] = (t == 0) ? 0 : sh[t - 1];
}

__global__ void k_scanC(int* __restrict__ rowptr, const int* __restrict__ bsum,
                        int* __restrict__ cursor) {
    int i = blockIdx.x * SCAN_BS + threadIdx.x;
    if (i < NN) {
        int rp = rowptr[i] + bsum[blockIdx.x];
        rowptr[i] = rp;
        cursor[i] = rp;
    }
    if (i == 0) rowptr[NN] = NE;
}

// XCD-partitioned CSR scatter
__global__ void k_build(const int* __restrict__ src, const int* __restrict__ dst,
                        int* __restrict__ cursor, int* __restrict__ ecol) {
    int g = blockIdx.x & 7;
    int b = blockIdx.x >> 3;
    int lo = g * GRP_ROWS, hi = lo + GRP_ROWS;
    for (int e = b * blockDim.x + threadIdx.x; e < NE; e += BUILD_BPG * blockDim.x) {
        int d = dst[e];
        if (d >= lo && d < hi) {
            int pos = atomicAdd(&cursor[d], 1);
            ecol[pos] = src[e];
        }
    }
}

// xe = x[NN,16] @ W[16,64] + b
__global__ void k_embed(const float* __restrict__ x, const float* __restrict__ W,
                        const float* __restrict__ b, float* __restrict__ xe) {
    __shared__ float Ws[16 * 64];
    __shared__ float bs[64];
    int t = threadIdx.x;
    for (int i = t; i < 16 * 64; i += 256) Ws[i] = W[i];
    if (t < 64) bs[t] = b[t];
    __syncthreads();
    int c = t & 63, r = t >> 6;
    int n0 = blockIdx.x * 64;
    for (int n = n0 + r; n < n0 + 64 && n < NN; n += 4) {
        const float* xr = x + n * 16;
        float acc = bs[c];
#pragma unroll
        for (int k = 0; k < 16; k++) acc = fmaf(xr[k], Ws[k * 64 + c], acc);
        xe[n * 64 + c] = acc;
    }
}

// fused: xe += relu(agg*sc+sh) (prev BN, if apply); hwb = bf16(dinv*(xe@W))
__global__ void k_hw(const float* __restrict__ xeIn, float* __restrict__ xe,
                     const float* __restrict__ W, const float* __restrict__ dinv,
                     const float* __restrict__ agg, const float* __restrict__ ss,
                     unsigned short* __restrict__ hwb, double* __restrict__ sums,
                     int apply) {
    __shared__ float Ws[64 * 64];     // Ws[k][c]
    __shared__ float Xs[64 * 65];     // Xs[n][k], +1 pad
    int t = threadIdx.x;
    if (blockIdx.x == 0) {
        for (int i = t; i < 16 * 128; i += 256) sums[i] = 0.0;
    }
#pragma unroll
    for (int i = 0; i < 4; i++)
        ((float4*)Ws)[t + i * 256] = ((const float4*)W)[t + i * 256];
    int c = t & 63, rr = t >> 6;
    int n0 = blockIdx.x * 64;
#pragma unroll
    for (int i = 0; i < 16; i++) {
        int rl = i * 4 + rr;
        int n = n0 + rl;
        float xv = 0.f;
        if (n < NN) {
            xv = xeIn[n * 64 + c];
            if (apply) {
                float v = fmaf(agg[n * 64 + c], ss[c], ss[64 + c]);
                xv += fmaxf(v, 0.f);
                xe[n * 64 + c] = xv;
            }
        }
        Xs[rl * 65 + c] = xv;
    }
    __syncthreads();

    int r0 = (t >> 4) * 4, c0 = (t & 15) * 4;
    float acc[4][4];
#pragma unroll
    for (int a = 0; a < 4; a++)
#pragma unroll
        for (int b = 0; b < 4; b++) acc[a][b] = 0.f;
    for (int k = 0; k < 64; k++) {
        float4 wv = *(const float4*)&Ws[k * 64 + c0];
        float x0 = Xs[(r0 + 0) * 65 + k];
        float x1 = Xs[(r0 + 1) * 65 + k];
        float x2 = Xs[(r0 + 2) * 65 + k];
        float x3 = Xs[(r0 + 3) * 65 + k];
        acc[0][0] = fmaf(x0, wv.x, acc[0][0]); acc[0][1] = fmaf(x0, wv.y, acc[0][1]);
        acc[0][2] = fmaf(x0, wv.z, acc[0][2]); acc[0][3] = fmaf(x0, wv.w, acc[0][3]);
        acc[1][0] = fmaf(x1, wv.x, acc[1][0]); acc[1][1] = fmaf(x1, wv.y, acc[1][1]);
        acc[1][2] = fmaf(x1, wv.z, acc[1][2]); acc[1][3] = fmaf(x1, wv.w, acc[1][3]);
        acc[2][0] = fmaf(x2, wv.x, acc[2][0]); acc[2][1] = fmaf(x2, wv.y, acc[2][1]);
        acc[2][2] = fmaf(x2, wv.z, acc[2][2]); acc[2][3] = fmaf(x2, wv.w, acc[2][3]);
        acc[3][0] = fmaf(x3, wv.x, acc[3][0]); acc[3][1] = fmaf(x3, wv.y, acc[3][1]);
        acc[3][2] = fmaf(x3, wv.z, acc[3][2]); acc[3][3] = fmaf(x3, wv.w, acc[3][3]);
    }
#pragma unroll
    for (int a = 0; a < 4; a++) {
        int n = n0 + r0 + a;
        if (n < NN) {
            float di = dinv[n];
            float v0 = acc[a][0] * di, v1 = acc[a][1] * di;
            float v2 = acc[a][2] * di, v3 = acc[a][3] * di;
            uint2 pk;
            pk.x = ((unsigned)f2bf(v1) << 16) | f2bf(v0);
            pk.y = ((unsigned)f2bf(v3) << 16) | f2bf(v2);
            *(uint2*)(hwb + n * 64 + c0) = pk;
        }
    }
}

// agg[d] = dinv[d]*(hwb[d] + sum_{s in N(d)} hwb[s]); fused BN stats.
// Wave = 1 row; 8 groups of 8 lanes stride the edge list; lane q holds ch 8q..8q+7
// (uint4 = 16B/lane gather: one VMEM instr covers 8 edge-rows, 2x fewer than R5)
__global__ void k_spmm(const int* __restrict__ rowptr, const int* __restrict__ ecol,
                       const unsigned short* __restrict__ hwb, const float* __restrict__ dinv,
                       float* __restrict__ agg, double* __restrict__ sums) {
    int t = threadIdx.x;
    int w = t >> 6, l = t & 63;
    int grp = l >> 3, q = l & 7;
    const uint4* hw4 = (const uint4*)hwb;   // row s = hw4[s*8 .. s*8+7]
    float ls[8], lq[8];
#pragma unroll
    for (int j = 0; j < 8; j++) { ls[j] = 0.f; lq[j] = 0.f; }
    for (int row = blockIdx.x * 4 + w; row < NN; row += SPMM_BLOCKS * 4) {
        int p0 = __builtin_amdgcn_readfirstlane(rowptr[row]);
        int p1 = __builtin_amdgcn_readfirstlane(rowptr[row + 1]);
        uint4 sv = hw4[row * 8 + q];
        float a[8];
#pragma unroll
        for (int j = 0; j < 8; j++) a[j] = 0.f;
        int p = p0 + grp;
        for (; p + 8 < p1; p += 16) {       // unroll 2: 16 edges per wave-iter
            int s0 = ecol[p], s1 = ecol[p + 8];
            uint4 u0 = hw4[s0 * 8 + q];
            uint4 u1 = hw4[s1 * 8 + q];
            a[0] += bflo(u0.x); a[1] += bfhi(u0.x); a[2] += bflo(u0.y); a[3] += bfhi(u0.y);
            a[4] += bflo(u0.z); a[5] += bfhi(u0.z); a[6] += bflo(u0.w); a[7] += bfhi(u0.w);
            a[0] += bflo(u1.x); a[1] += bfhi(u1.x); a[2] += bflo(u1.y); a[3] += bfhi(u1.y);
            a[4] += bflo(u1.z); a[5] += bfhi(u1.z); a[6] += bflo(u1.w); a[7] += bfhi(u1.w);
        }
        if (p < p1) {
            int s0 = ecol[p];
            uint4 u0 = hw4[s0 * 8 + q];
            a[0] += bflo(u0.x); a[1] += bfhi(u0.x); a[2] += bflo(u0.y); a[3] += bfhi(u0.y);
            a[4] += bflo(u0.z); a[5] += bfhi(u0.z); a[6] += bflo(u0.w); a[7] += bfhi(u0.w);
        }
        // reduce across the 8 groups (lane bits 3,4,5); butterfly -> all lanes hold total
#pragma unroll
        for (int j = 0; j < 8; j++) {
            a[j] += __shfl_xor(a[j], 8, 64);
            a[j] += __shfl_xor(a[j], 16, 64);
            a[j] += __shfl_xor(a[j], 32, 64);
        }
        float di = dinv[row];
        float v[8];
        v[0] = (a[0] + bflo(sv.x)) * di; v[1] = (a[1] + bfhi(sv.x)) * di;
        v[2] = (a[2] + bflo(sv.y)) * di; v[3] = (a[3] + bfhi(sv.y)) * di;
        v[4] = (a[4] + bflo(sv.z)) * di; v[5] = (a[5] + bfhi(sv.z)) * di;
        v[6] = (a[6] + bflo(sv.w)) * di; v[7] = (a[7] + bfhi(sv.w)) * di;
        if (grp == 0) {                     // 8 lanes x 32B = 256B row store
            float4 o0 = make_float4(v[0], v[1], v[2], v[3]);
            float4 o1 = make_float4(v[4], v[5], v[6], v[7]);
            *(float4*)(agg + row * 64 + 8 * q) = o0;
            *(float4*)(agg + row * 64 + 8 * q + 4) = o1;
#pragma unroll
            for (int j = 0; j < 8; j++) {
                ls[j] += v[j];
                lq[j] = fmaf(v[j], v[j], lq[j]);
            }
        }
    }
    __shared__ float Ss[4][64], Sq[4][64];
    if (grp == 0) {
#pragma unroll
        for (int j = 0; j < 8; j++) {
            Ss[w][8 * q + j] = ls[j];
            Sq[w][8 * q + j] = lq[j];
        }
    }
    __syncthreads();
    if (t < 64) {
        float a = Ss[0][t] + Ss[1][t] + Ss[2][t] + Ss[3][t];
        float b = Sq[0][t] + Sq[1][t] + Sq[2][t] + Sq[3][t];
        double* sh = sums + (blockIdx.x & 15) * 128;
        atomicAdd(&sh[t], (double)a);
        atomicAdd(&sh[64 + t], (double)b);
    }
}

__global__ void k_finalize(const double* __restrict__ sums, const float* __restrict__ gamma,
                           const float* __restrict__ beta, float* __restrict__ ss) {
    int c = threadIdx.x;  // 64 threads
    double s = 0.0, q = 0.0;
#pragma unroll
    for (int k = 0; k < 16; k++) { s += sums[k * 128 + c]; q += sums[k * 128 + 64 + c]; }
    double mean = s / (double)NN;
    double var = q / (double)NN - mean * mean;
    float sc = gamma[c] * rsqrtf((float)var + BN_EPS);
    ss[c] = sc;
    ss[64 + c] = beta[c] - (float)mean * sc;
}

// final layer: xe += relu(agg*scale + shift)
__global__ void k_apply(const float* __restrict__ agg, const float* __restrict__ ss,
                        float* __restrict__ xe) {
    int i = blockIdx.x * blockDim.x + threadIdx.x;
    if (i < NN * HID) {
        int c = i & 63;
        float v = fmaf(agg[i], ss[c], ss[64 + c]);
        xe[i] += fmaxf(v, 0.f);
    }
}

// out[e] = [xe[s]; xe[d]] @ fc_W + fc_b
__global__ void k_out(const int* __restrict__ esrc, const int* __restrict__ edst,
                      const float* __restrict__ xe, const float* __restrict__ fcW,
                      const float* __restrict__ fcb, float* __restrict__ out) {
    __shared__ float Ws[256];
    __shared__ float bs[2];
    int t = threadIdx.x;
    for (int i = t; i < 256; i += 256) Ws[i] = fcW[i];
    if (t < 2) bs[t] = fcb[t];
    __syncthreads();
    int e = blockIdx.x * blockDim.x + t;
    if (e < NEO) {
        int s = esrc[e], d = edst[e];
        const float4* rs = (const float4*)(xe + s * 64);
        const float4* rd = (const float4*)(xe + d * 64);
        float a0 = bs[0], a1 = bs[1];
#pragma unroll
        for (int i = 0; i < 16; i++) {
            float4 v = rs[i];
            a0 += v.x * Ws[(i * 4 + 0) * 2] + v.y * Ws[(i * 4 + 1) * 2] +
                  v.z * Ws[(i * 4 + 2) * 2] + v.w * Ws[(i * 4 + 3) * 2];
            a1 += v.x * Ws[(i * 4 + 0) * 2 + 1] + v.y * Ws[(i * 4 + 1) * 2 + 1] +
                  v.z * Ws[(i * 4 + 2) * 2 + 1] + v.w * Ws[(i * 4 + 3) * 2 + 1];
        }
#pragma unroll
        for (int i = 0; i < 16; i++) {
            float4 v = rd[i];
            a0 += v.x * Ws[(64 + i * 4 + 0) * 2] + v.y * Ws[(64 + i * 4 + 1) * 2] +
                  v.z * Ws[(64 + i * 4 + 2) * 2] + v.w * Ws[(64 + i * 4 + 3) * 2];
            a1 += v.x * Ws[(64 + i * 4 + 0) * 2 + 1] + v.y * Ws[(64 + i * 4 + 1) * 2 + 1] +
                  v.z * Ws[(64 + i * 4 + 2) * 2 + 1] + v.w * Ws[(64 + i * 4 + 3) * 2 + 1];
        }
        out[e * 2] = a0;
        out[e * 2 + 1] = a1;
    }
}

extern "C" void kernel_launch(void* const* d_in, const int* in_sizes, int n_in,
                              void* d_out, int out_size, void* d_ws, size_t ws_size,
                              hipStream_t stream) {
    const float* x      = (const float*)d_in[0];
    const int*   ei     = (const int*)d_in[1];
    const int*   eio    = (const int*)d_in[2];
    const float* W_emb  = (const float*)d_in[3];
    const float* b_emb  = (const float*)d_in[4];
    const float* conv_W = (const float*)d_in[5];
    // d_in[6] conv_b: cancels inside BN
    const float* bn_g   = (const float*)d_in[7];
    const float* bn_b   = (const float*)d_in[8];
    const float* fc_W   = (const float*)d_in[9];
    const float* fc_b   = (const float*)d_in[10];
    float* out = (float*)d_out;

    float* ws   = (float*)d_ws;
    int*   ecol = (int*)(ws + OFF_ECOL);
    float* xe   = ws + OFF_XE;
    float* agg  = ws + OFF_AGG;
    unsigned short* hwb = (unsigned short*)(ws + OFF_HWB);

    float* od     = (float*)d_out;
    float* dinv   = od + OD_DINV;
    int*   rowptr = (int*)(od + OD_ROWPTR);
    int*   cc     = (int*)(od + OD_CC);
    int*   bsum   = (int*)(od + OD_BSUM);
    float* ss     = od + OD_SS;
    double* sums  = (double*)(od + OD_SUMS);

    const int* src  = ei;
    const int* dst  = ei + NE;
    const int* esrc = eio;
    const int* edst = eio + NEO;

    // ---- one-time CSR build (XCD-partitioned) ----
    (void)hipMemsetAsync(cc, 0, NN * sizeof(int), stream);
    k_hist<<<8 * BUILD_BPG, 256, 0, stream>>>(dst, cc);
    k_scanA<<<SCAN_NB, SCAN_BS, 0, stream>>>(cc, rowptr, bsum, dinv);
    k_scanB<<<1, 256, 0, stream>>>(bsum);
    k_scanC<<<SCAN_NB, SCAN_BS, 0, stream>>>(rowptr, bsum, cc);
    k_build<<<8 * BUILD_BPG, 256, 0, stream>>>(src, dst, cc, ecol);

    k_embed<<<(NN + 63) / 64, 256, 0, stream>>>(x, W_emb, b_emb, xe);

    for (int l = 0; l < NL; l++) {
        k_hw<<<(NN + 63) / 64, 256, 0, stream>>>(xe, xe, conv_W + l * 64 * 64, dinv,
                                                 agg, ss, hwb, sums, l > 0 ? 1 : 0);
        k_spmm<<<SPMM_BLOCKS, 256, 0, stream>>>(rowptr, ecol, hwb, dinv, agg, sums);
        k_finalize<<<1, 64, 0, stream>>>(sums, bn_g + l * 64, bn_b + l * 64, ss);
    }
    k_apply<<<(NN * HID) / 256, 256, 0, stream>>>(agg, ss, xe);

    k_out<<<(NEO + 255) / 256, 256, 0, stream>>>(esrc, edst, xe, fc_W, fc_b, out);
}

// Round 9
// 634.837 us; speedup vs baseline: 1.4079x; 1.1484x over previous
//
#include <hip/hip_runtime.h>

#define NN 100000
#define NE 1600000
#define NEO 400000
#define HID 64
#define NL 6
#define BN_EPS 1e-5f

#define SPMM_BLOCKS 2048
#define SCAN_BS 512
#define SCAN_NB 196   // ceil(100000/512)
#define GRP_ROWS 12500          // NN/8 rows per XCD group
#define BUILD_BPG 784           // blocks per group for hist/build

// ---- d_ws layout (float offsets): 70.4MB ----
#define OFF_ECOL 0                        // NE ints
#define OFF_XE   NE                       // NN*64 f
#define OFF_AGG  (OFF_XE + NN * HID)      // NN*64 f
#define OFF_HWB  (OFF_AGG + NN * HID)     // NN*64 bf16 = NN*32 f

// ---- d_out head used as scratch (dead before k_out overwrites) ----
#define OD_DINV   0                      // NN f
#define OD_ROWPTR 100000                 // NN+1 ints (rounded 100352)
#define OD_CC     200352                 // NN ints (counts, then cursors)
#define OD_BSUM   300352                 // 256 ints
#define OD_SS     300608                 // 128 f (scale/shift)
#define OD_SUMS   300736                 // 16*128 doubles

typedef __attribute__((ext_vector_type(8))) short bf16x8;
typedef __attribute__((ext_vector_type(4))) float f32x4;

static __device__ __forceinline__ unsigned short f2bf(float f) {
    unsigned u = __float_as_uint(f);
    unsigned r = (u + 0x7FFF + ((u >> 16) & 1)) >> 16;  // RNE
    return (unsigned short)r;
}
static __device__ __forceinline__ float bflo(unsigned u) {
    return __uint_as_float(u << 16);
}
static __device__ __forceinline__ float bfhi(unsigned u) {
    return __uint_as_float(u & 0xFFFF0000u);
}

// XCD-partitioned histogram (validated win R4->R5)
__global__ void k_hist(const int* __restrict__ dst, int* __restrict__ cnt) {
    int g = blockIdx.x & 7;
    int b = blockIdx.x >> 3;
    int lo = g * GRP_ROWS, hi = lo + GRP_ROWS;
    for (int e = b * blockDim.x + threadIdx.x; e < NE; e += BUILD_BPG * blockDim.x) {
        int d = dst[e];
        if (d >= lo && d < hi) atomicAdd(&cnt[d], 1);
    }
}

__global__ void k_scanA(const int* __restrict__ cnt, int* __restrict__ rowptr,
                        int* __restrict__ bsum, float* __restrict__ dinv) {
    __shared__ int sh[SCAN_BS];
    int t = threadIdx.x;
    int i = blockIdx.x * SCAN_BS + t;
    int v = (i < NN) ? cnt[i] : 0;
    sh[t] = v;
    __syncthreads();
    for (int off = 1; off < SCAN_BS; off <<= 1) {
        int a = (t >= off) ? sh[t - off] : 0;
        __syncthreads();
        sh[t] += a;
        __syncthreads();
    }
    if (i < NN) {
        rowptr[i] = sh[t] - v;
        dinv[i] = rsqrtf((float)(v + 1));   // deg = in-deg + self-loop
    }
    if (t == SCAN_BS - 1) bsum[blockIdx.x] = sh[t];
}

__global__ void k_scanB(int* __restrict__ bsum) {
    __shared__ int sh[256];
    int t = threadIdx.x;
    int v = (t < SCAN_NB) ? bsum[t] : 0;
    sh[t] = v;
    __syncthreads();
    for (int off = 1; off < 256; off <<= 1) {
        int a = (t >= off) ? sh[t - off] : 0;
        __syncthreads();
        sh[t] += a;
        __syncthreads();
    }
    if (t < SCAN_NB) bsum[t] = (t == 0) ? 0 : sh[t - 1];
}

__global__ void k_scanC(int* __restrict__ rowptr, const int* __restrict__ bsum,
                        int* __restrict__ cursor) {
    int i = blockIdx.x * SCAN_BS + threadIdx.x;
    if (i < NN) {
        int rp = rowptr[i] + bsum[blockIdx.x];
        rowptr[i] = rp;
        cursor[i] = rp;
    }
    if (i == 0) rowptr[NN] = NE;
}

// XCD-partitioned CSR scatter
__global__ void k_build(const int* __restrict__ src, const int* __restrict__ dst,
                        int* __restrict__ cursor, int* __restrict__ ecol) {
    int g = blockIdx.x & 7;
    int b = blockIdx.x >> 3;
    int lo = g * GRP_ROWS, hi = lo + GRP_ROWS;
    for (int e = b * blockDim.x + threadIdx.x; e < NE; e += BUILD_BPG * blockDim.x) {
        int d = dst[e];
        if (d >= lo && d < hi) {
            int pos = atomicAdd(&cursor[d], 1);
            ecol[pos] = src[e];
        }
    }
}

// xe = x[NN,16] @ W[16,64] + b
__global__ void k_embed(const float* __restrict__ x, const float* __restrict__ W,
                        const float* __restrict__ b, float* __restrict__ xe) {
    __shared__ float Ws[16 * 64];
    __shared__ float bs[64];
    int t = threadIdx.x;
    for (int i = t; i < 16 * 64; i += 256) Ws[i] = W[i];
    if (t < 64) bs[t] = b[t];
    __syncthreads();
    int c = t & 63, r = t >> 6;
    int n0 = blockIdx.x * 64;
    for (int n = n0 + r; n < n0 + 64 && n < NN; n += 4) {
        const float* xr = x + n * 16;
        float acc = bs[c];
#pragma unroll
        for (int k = 0; k < 16; k++) acc = fmaf(xr[k], Ws[k * 64 + c], acc);
        xe[n * 64 + c] = acc;
    }
}

// fused: xe += relu(agg*sc+sh) (prev BN, if apply); hwb = bf16(dinv*(xe@W))
// MFMA version: D[ch][node] = Wt(ch,k) x Xb(k,node), 16x16x32 bf16.
// A frag: A[m=lane&15][k=quad*8+j] -> Wt[c][k] rows; B frag: B[k][n=lane&15] -> Xb[n][k] rows.
// D: row(=ch)=quad*4+reg, col(=node)=lane&15 -> 4 consecutive channels/lane = uint2 store.
__global__ void k_hw(const float* __restrict__ xeIn, float* __restrict__ xe,
                     const float* __restrict__ W, const float* __restrict__ dinv,
                     const float* __restrict__ agg, const float* __restrict__ ss,
                     unsigned short* __restrict__ hwb, double* __restrict__ sums,
                     int apply) {
    __shared__ unsigned short Wt[64 * 72];   // Wt[c][k], pitch 72 (16B-aligned, 2-way banks)
    __shared__ unsigned short Xb[64 * 72];   // Xb[n][k]
    __shared__ float sss[128];
    int t = threadIdx.x;
    int n0 = blockIdx.x * 64;
    if (blockIdx.x == 0) {
        for (int i = t; i < 16 * 128; i += 256) sums[i] = 0.0;
    }
    if (t < 128) sss[t] = apply ? ss[t] : 0.f;

    {   // stage Wt (transpose, bf16): thread (c=t&63, r=t>>6) covers k=r*16..+15
        int c = t & 63, r = t >> 6;
#pragma unroll
        for (int jj = 0; jj < 4; jj++) {
            float w0 = W[(r * 16 + jj * 4 + 0) * 64 + c];
            float w1 = W[(r * 16 + jj * 4 + 1) * 64 + c];
            float w2 = W[(r * 16 + jj * 4 + 2) * 64 + c];
            float w3 = W[(r * 16 + jj * 4 + 3) * 64 + c];
            uint2 pk;
            pk.x = ((unsigned)f2bf(w1) << 16) | f2bf(w0);
            pk.y = ((unsigned)f2bf(w3) << 16) | f2bf(w2);
            *(uint2*)&Wt[c * 72 + r * 16 + jj * 4] = pk;
        }
    }
    __syncthreads();   // sss ready (Xb staging reads it)

    {   // stage Xb (+apply fusion): thread (n=t>>2, kq=t&3) covers k=kq*16..+15
        int n = t >> 2, kq = t & 3;
        int node = n0 + n;
        float4 xv[4];
        if (node < NN) {
            const float4* xr = (const float4*)(xeIn + (size_t)node * 64 + kq * 16);
#pragma unroll
            for (int i = 0; i < 4; i++) xv[i] = xr[i];
            if (apply) {
                const float4* ar = (const float4*)(agg + (size_t)node * 64 + kq * 16);
                float4* xw = (float4*)(xe + (size_t)node * 64 + kq * 16);
#pragma unroll
                for (int i = 0; i < 4; i++) {
                    float4 av = ar[i];
                    int c = kq * 16 + i * 4;
                    xv[i].x += fmaxf(fmaf(av.x, sss[c + 0], sss[64 + c + 0]), 0.f);
                    xv[i].y += fmaxf(fmaf(av.y, sss[c + 1], sss[64 + c + 1]), 0.f);
                    xv[i].z += fmaxf(fmaf(av.z, sss[c + 2], sss[64 + c + 2]), 0.f);
                    xv[i].w += fmaxf(fmaf(av.w, sss[c + 3], sss[64 + c + 3]), 0.f);
                    xw[i] = xv[i];
                }
            }
        } else {
#pragma unroll
            for (int i = 0; i < 4; i++) xv[i] = make_float4(0.f, 0.f, 0.f, 0.f);
        }
#pragma unroll
        for (int i = 0; i < 4; i++) {
            uint2 pk;
            pk.x = ((unsigned)f2bf(xv[i].y) << 16) | f2bf(xv[i].x);
            pk.y = ((unsigned)f2bf(xv[i].w) << 16) | f2bf(xv[i].z);
            *(uint2*)&Xb[n * 72 + kq * 16 + i * 4] = pk;
        }
    }
    __syncthreads();

    int lane = t & 63, w = t >> 6;
    int m = lane & 15, quad = lane >> 4;
    f32x4 acc[4];
#pragma unroll
    for (int tc = 0; tc < 4; tc++) acc[tc] = (f32x4){0.f, 0.f, 0.f, 0.f};
#pragma unroll
    for (int s = 0; s < 2; s++) {
        bf16x8 bfr = *(const bf16x8*)&Xb[(w * 16 + m) * 72 + s * 32 + quad * 8];
#pragma unroll
        for (int tc = 0; tc < 4; tc++) {
            bf16x8 afr = *(const bf16x8*)&Wt[(tc * 16 + m) * 72 + s * 32 + quad * 8];
            acc[tc] = __builtin_amdgcn_mfma_f32_16x16x32_bf16(afr, bfr, acc[tc], 0, 0, 0);
        }
    }
    int node = n0 + w * 16 + m;
    if (node < NN) {
        float di = dinv[node];
#pragma unroll
        for (int tc = 0; tc < 4; tc++) {
            int c0 = tc * 16 + quad * 4;
            uint2 pk;
            pk.x = ((unsigned)f2bf(acc[tc][1] * di) << 16) | f2bf(acc[tc][0] * di);
            pk.y = ((unsigned)f2bf(acc[tc][3] * di) << 16) | f2bf(acc[tc][2] * di);
            *(uint2*)(hwb + (size_t)node * 64 + c0) = pk;
        }
    }
}

// agg[d] = dinv[d]*(hwb[d] + sum_{s in N(d)} hwb[s]); fused BN stats.
// Wave = 4 rows x 16 lanes (2 sub-groups of 8); lane q holds ch 8q..8q+7 (uint4).
// Cross-group reduce = ONE shfl step (8 shuffles / 4 rows, vs 24/row before).
__global__ void k_spmm(const int* __restrict__ rowptr, const int* __restrict__ ecol,
                       const unsigned short* __restrict__ hwb, const float* __restrict__ dinv,
                       float* __restrict__ agg, double* __restrict__ sums) {
    int t = threadIdx.x;
    int w = t >> 6, l = t & 63;
    int r = l >> 4;          // row slot 0..3
    int sub = (l >> 3) & 1;  // edge sub-group
    int q = l & 7;           // channel quad
    const uint4* hw4 = (const uint4*)hwb;
    float ls[8], lq[8];
#pragma unroll
    for (int j = 0; j < 8; j++) { ls[j] = 0.f; lq[j] = 0.f; }
    for (int row0 = blockIdx.x * 16 + w * 4; row0 < NN; row0 += SPMM_BLOCKS * 16) {
        int row = row0 + r;
        bool valid = row < NN;
        int p0 = 0, p1 = 0;
        float a[8];
#pragma unroll
        for (int j = 0; j < 8; j++) a[j] = 0.f;
        if (valid) {
            p0 = rowptr[row];
            p1 = rowptr[row + 1];
            if (sub == 0) {   // count self-term once
                uint4 sv = hw4[(size_t)row * 8 + q];
                a[0] = bflo(sv.x); a[1] = bfhi(sv.x); a[2] = bflo(sv.y); a[3] = bfhi(sv.y);
                a[4] = bflo(sv.z); a[5] = bfhi(sv.z); a[6] = bflo(sv.w); a[7] = bfhi(sv.w);
            }
        }
        int p = p0 + sub;
        for (; p + 2 < p1; p += 4) {      // unroll 2: 2 edges/sub-group in flight
            int s0 = ecol[p], s1 = ecol[p + 2];
            uint4 u0 = hw4[(size_t)s0 * 8 + q];
            uint4 u1 = hw4[(size_t)s1 * 8 + q];
            a[0] += bflo(u0.x); a[1] += bfhi(u0.x); a[2] += bflo(u0.y); a[3] += bfhi(u0.y);
            a[4] += bflo(u0.z); a[5] += bfhi(u0.z); a[6] += bflo(u0.w); a[7] += bfhi(u0.w);
            a[0] += bflo(u1.x); a[1] += bfhi(u1.x); a[2] += bflo(u1.y); a[3] += bfhi(u1.y);
            a[4] += bflo(u1.z); a[5] += bfhi(u1.z); a[6] += bflo(u1.w); a[7] += bfhi(u1.w);
        }
        if (p < p1) {
            int s0 = ecol[p];
            uint4 u0 = hw4[(size_t)s0 * 8 + q];
            a[0] += bflo(u0.x); a[1] += bfhi(u0.x); a[2] += bflo(u0.y); a[3] += bfhi(u0.y);
            a[4] += bflo(u0.z); a[5] += bfhi(u0.z); a[6] += bflo(u0.w); a[7] += bfhi(u0.w);
        }
#pragma unroll
        for (int j = 0; j < 8; j++) a[j] += __shfl_xor(a[j], 8, 64);  // merge sub-groups
        if (valid && sub == 0) {
            float di = dinv[row];
            float v[8];
#pragma unroll
            for (int j = 0; j < 8; j++) v[j] = a[j] * di;
            float4 o0 = make_float4(v[0], v[1], v[2], v[3]);
            float4 o1 = make_float4(v[4], v[5], v[6], v[7]);
            *(float4*)(agg + (size_t)row * 64 + 8 * q) = o0;
            *(float4*)(agg + (size_t)row * 64 + 8 * q + 4) = o1;
#pragma unroll
            for (int j = 0; j < 8; j++) {
                ls[j] += v[j];
                lq[j] = fmaf(v[j], v[j], lq[j]);
            }
        }
    }
    // reduce stats across the 4 row-slots (lane bits 4,5); sub-bit untouched
#pragma unroll
    for (int j = 0; j < 8; j++) {
        ls[j] += __shfl_xor(ls[j], 16, 64); ls[j] += __shfl_xor(ls[j], 32, 64);
        lq[j] += __shfl_xor(lq[j], 16, 64); lq[j] += __shfl_xor(lq[j], 32, 64);
    }
    __shared__ float Ss[4][64], Sq[4][64];
    if (l < 8) {   // r==0, sub==0, q=l
#pragma unroll
        for (int j = 0; j < 8; j++) {
            Ss[w][8 * l + j] = ls[j];
            Sq[w][8 * l + j] = lq[j];
        }
    }
    __syncthreads();
    if (t < 64) {
        float a = Ss[0][t] + Ss[1][t] + Ss[2][t] + Ss[3][t];
        float b = Sq[0][t] + Sq[1][t] + Sq[2][t] + Sq[3][t];
        double* sh = sums + (blockIdx.x & 15) * 128;
        atomicAdd(&sh[t], (double)a);
        atomicAdd(&sh[64 + t], (double)b);
    }
}

__global__ void k_finalize(const double* __restrict__ sums, const float* __restrict__ gamma,
                           const float* __restrict__ beta, float* __restrict__ ss) {
    int c = threadIdx.x;  // 64 threads
    double s = 0.0, q = 0.0;
#pragma unroll
    for (int k = 0; k < 16; k++) { s += sums[k * 128 + c]; q += sums[k * 128 + 64 + c]; }
    double mean = s / (double)NN;
    double var = q / (double)NN - mean * mean;
    float sc = gamma[c] * rsqrtf((float)var + BN_EPS);
    ss[c] = sc;
    ss[64 + c] = beta[c] - (float)mean * sc;
}

// final layer: xe += relu(agg*scale + shift)
__global__ void k_apply(const float* __restrict__ agg, const float* __restrict__ ss,
                        float* __restrict__ xe) {
    int i = blockIdx.x * blockDim.x + threadIdx.x;
    if (i < NN * HID) {
        int c = i & 63;
        float v = fmaf(agg[i], ss[c], ss[64 + c]);
        xe[i] += fmaxf(v, 0.f);
    }
}

// out[e] = [xe[s]; xe[d]] @ fc_W + fc_b
__global__ void k_out(const int* __restrict__ esrc, const int* __restrict__ edst,
                      const float* __restrict__ xe, const float* __restrict__ fcW,
                      const float* __restrict__ fcb, float* __restrict__ out) {
    __shared__ float Ws[256];
    __shared__ float bs[2];
    int t = threadIdx.x;
    for (int i = t; i < 256; i += 256) Ws[i] = fcW[i];
    if (t < 2) bs[t] = fcb[t];
    __syncthreads();
    int e = blockIdx.x * blockDim.x + t;
    if (e < NEO) {
        int s = esrc[e], d = edst[e];
        const float4* rs = (const float4*)(xe + s * 64);
        const float4* rd = (const float4*)(xe + d * 64);
        float a0 = bs[0], a1 = bs[1];
#pragma unroll
        for (int i = 0; i < 16; i++) {
            float4 v = rs[i];
            a0 += v.x * Ws[(i * 4 + 0) * 2] + v.y * Ws[(i * 4 + 1) * 2] +
                  v.z * Ws[(i * 4 + 2) * 2] + v.w * Ws[(i * 4 + 3) * 2];
            a1 += v.x * Ws[(i * 4 + 0) * 2 + 1] + v.y * Ws[(i * 4 + 1) * 2 + 1] +
                  v.z * Ws[(i * 4 + 2) * 2 + 1] + v.w * Ws[(i * 4 + 3) * 2 + 1];
        }
#pragma unroll
        for (int i = 0; i < 16; i++) {
            float4 v = rd[i];
            a0 += v.x * Ws[(64 + i * 4 + 0) * 2] + v.y * Ws[(64 + i * 4 + 1) * 2] +
                  v.z * Ws[(64 + i * 4 + 2) * 2] + v.w * Ws[(64 + i * 4 + 3) * 2];
            a1 += v.x * Ws[(64 + i * 4 + 0) * 2 + 1] + v.y * Ws[(64 + i * 4 + 1) * 2 + 1] +
                  v.z * Ws[(64 + i * 4 + 2) * 2 + 1] + v.w * Ws[(64 + i * 4 + 3) * 2 + 1];
        }
        out[e * 2] = a0;
        out[e * 2 + 1] = a1;
    }
}

extern "C" void kernel_launch(void* const* d_in, const int* in_sizes, int n_in,
                              void* d_out, int out_size, void* d_ws, size_t ws_size,
                              hipStream_t stream) {
    const float* x      = (const float*)d_in[0];
    const int*   ei     = (const int*)d_in[1];
    const int*   eio    = (const int*)d_in[2];
    const float* W_emb  = (const float*)d_in[3];
    const float* b_emb  = (const float*)d_in[4];
    const float* conv_W = (const float*)d_in[5];
    // d_in[6] conv_b: cancels inside BN
    const float* bn_g   = (const float*)d_in[7];
    const float* bn_b   = (const float*)d_in[8];
    const float* fc_W   = (const float*)d_in[9];
    const float* fc_b   = (const float*)d_in[10];
    float* out = (float*)d_out;

    float* ws   = (float*)d_ws;
    int*   ecol = (int*)(ws + OFF_ECOL);
    float* xe   = ws + OFF_XE;
    float* agg  = ws + OFF_AGG;
    unsigned short* hwb = (unsigned short*)(ws + OFF_HWB);

    float* od     = (float*)d_out;
    float* dinv   = od + OD_DINV;
    int*   rowptr = (int*)(od + OD_ROWPTR);
    int*   cc     = (int*)(od + OD_CC);
    int*   bsum   = (int*)(od + OD_BSUM);
    float* ss     = od + OD_SS;
    double* sums  = (double*)(od + OD_SUMS);

    const int* src  = ei;
    const int* dst  = ei + NE;
    const int* esrc = eio;
    const int* edst = eio + NEO;

    // ---- one-time CSR build (XCD-partitioned) ----
    (void)hipMemsetAsync(cc, 0, NN * sizeof(int), stream);
    k_hist<<<8 * BUILD_BPG, 256, 0, stream>>>(dst, cc);
    k_scanA<<<SCAN_NB, SCAN_BS, 0, stream>>>(cc, rowptr, bsum, dinv);
    k_scanB<<<1, 256, 0, stream>>>(bsum);
    k_scanC<<<SCAN_NB, SCAN_BS, 0, stream>>>(rowptr, bsum, cc);
    k_build<<<8 * BUILD_BPG, 256, 0, stream>>>(src, dst, cc, ecol);

    k_embed<<<(NN + 63) / 64, 256, 0, stream>>>(x, W_emb, b_emb, xe);

    for (int l = 0; l < NL; l++) {
        k_hw<<<(NN + 63) / 64, 256, 0, stream>>>(xe, xe, conv_W + l * 64 * 64, dinv,
                                                 agg, ss, hwb, sums, l > 0 ? 1 : 0);
        k_spmm<<<SPMM_BLOCKS, 256, 0, stream>>>(rowptr, ecol, hwb, dinv, agg, sums);
        k_finalize<<<1, 64, 0, stream>>>(sums, bn_g + l * 64, bn_b + l * 64, ss);
    }
    k_apply<<<(NN * HID) / 256, 256, 0, stream>>>(agg, ss, xe);

    k_out<<<(NEO + 255) / 256, 256, 0, stream>>>(esrc, edst, xe, fc_W, fc_b, out);
}